// Round 10
// baseline (95.549 us; speedup 1.0000x reference)
//
#include <hip/hip_runtime.h>

#define HW 4096
#define C 64
#define H 8
#define D 8
#define S 8
#define KEYS_PER_SPLIT (HW / S)      // 512
#define TILES (KEYS_PER_SPLIT / 32)  // 16 tiles of 32 keys
#define L2E 1.44269504088896340736f
#define KROW 24                      // padded K row stride (bytes): bank period 16 -> 2-way reads
#define VROW 1032                    // sV row stride bytes

typedef _Float16 h2 __attribute__((ext_vector_type(2)));
typedef _Float16 half4 __attribute__((ext_vector_type(4)));
typedef float f32x16 __attribute__((ext_vector_type(16)));

static __device__ __forceinline__ float fast_exp2(float x) {
#if __has_builtin(__builtin_amdgcn_exp2f)
    return __builtin_amdgcn_exp2f(x);
#else
    return __exp2f(x);
#endif
}

static __device__ __forceinline__ h2 pack_h2(float a, float b) {
    return __builtin_bit_cast(h2, __builtin_amdgcn_cvt_pkrtz(a, b));
}

static __device__ __forceinline__ half4 cat_h2(h2 lo, h2 hi) {
    uint2 u;
    u.x = __builtin_bit_cast(unsigned, lo);
    u.y = __builtin_bit_cast(unsigned, hi);
    return __builtin_bit_cast(half4, u);
}

static __device__ __forceinline__ f32x16 mfma32(half4 a, half4 b, f32x16 c) {
    return __builtin_amdgcn_mfma_f32_32x32x8f16(a, b, c, 0, 0, 0);
}

static __device__ __forceinline__ float gnorm8(float a) {
    float ss = a * a;
    ss += __shfl_xor(ss, 1, 64);
    ss += __shfl_xor(ss, 2, 64);
    ss += __shfl_xor(ss, 4, 64);
    return 1.0f / fmaxf(sqrtf(ss), 1e-12f);
}

// Kernel 1: q/k/v projections + per-head l2 norm, fp16 outputs. (unchanged)
// Layouts: qh,kh = [H][HW][8] f16 (q pre-scaled by log2e); vt = [H*8][HW] f16.
__global__ __launch_bounds__(192) void proj_kernel(
    const float* __restrict__ x, const float* __restrict__ y,
    const float* __restrict__ Wq, const float* __restrict__ bq,
    const float* __restrict__ Wkv, const float* __restrict__ bkv,
    _Float16* __restrict__ qh, _Float16* __restrict__ kh, _Float16* __restrict__ vt)
{
    const int r0 = blockIdx.x * 4;
    const int wave = __builtin_amdgcn_readfirstlane((int)(threadIdx.x >> 6));
    const int j = threadIdx.x & 63;

    const float* __restrict__ W;
    const float* __restrict__ rows;
    int wstride;
    float bias;
    if (wave == 0)      { W = Wq + j;        wstride = C;     bias = bq[j];      rows = x + (size_t)r0 * C; }
    else if (wave == 1) { W = Wkv + j;       wstride = 2 * C; bias = bkv[j];     rows = y + (size_t)r0 * C; }
    else                { W = Wkv + C + j;   wstride = 2 * C; bias = bkv[C + j]; rows = y + (size_t)r0 * C; }

    float a0 = bias, a1 = bias, a2 = bias, a3 = bias;
    #pragma unroll
    for (int i = 0; i < C; ++i) {
        const float w = W[(size_t)i * wstride];
        a0 = fmaf(rows[i],         w, a0);
        a1 = fmaf(rows[C + i],     w, a1);
        a2 = fmaf(rows[2 * C + i], w, a2);
        a3 = fmaf(rows[3 * C + i], w, a3);
    }

    const int head = j >> 3;
    const int d = j & 7;
    if (wave == 0) {
        const float s0 = gnorm8(a0) * L2E, s1 = gnorm8(a1) * L2E;
        const float s2 = gnorm8(a2) * L2E, s3 = gnorm8(a3) * L2E;
        _Float16* p = qh + ((size_t)head * HW + r0) * D + d;
        p[0 * D] = (_Float16)(a0 * s0);
        p[1 * D] = (_Float16)(a1 * s1);
        p[2 * D] = (_Float16)(a2 * s2);
        p[3 * D] = (_Float16)(a3 * s3);
    } else if (wave == 1) {
        const float s0 = gnorm8(a0), s1 = gnorm8(a1);
        const float s2 = gnorm8(a2), s3 = gnorm8(a3);
        _Float16* p = kh + ((size_t)head * HW + r0) * D + d;
        p[0 * D] = (_Float16)(a0 * s0);
        p[1 * D] = (_Float16)(a1 * s1);
        p[2 * D] = (_Float16)(a2 * s2);
        p[3 * D] = (_Float16)(a3 * s3);
    } else {
        const h2 lo = pack_h2(a0, a1);
        const h2 hi = pack_h2(a2, a3);
        *(half4*)(vt + (size_t)j * HW + r0) = cat_h2(lo, hi);
    }
}

// Kernel 2: LDS-staged MFMA flash attention, 32x32x8 core, 2 q-tiles/wave.
// Block = 256 thr (4 waves) = (head h, 256 queries, 512-key split); wave w
// owns 64 queries (2 tiles of 32). Per 32-key tile:
//   QK: kf (shared LDS read) x {qfA,qfB} -> two independent S^T 32x32 tiles.
//   32 exp2 -> 8 half4 packs. C-layout reg group 4j+i holds key
//   8j+4*(lane>>5)+i == B-fragment k-index of PV MFMA j -> NO transpose.
//   PV: vf (shared LDS read) x {pbA_j, pbB_j} -> two INDEPENDENT O chains
//   (breaks the serial accumulation latency of a single chain).
//   V channel row 8 = ones -> O reg 4 (row 8) = softmax denominator.
// __launch_bounds__(256,4): VGPR cap 128 (O0,O1,c0,c1 = 64 regs + operands, no spill).
__global__ __launch_bounds__(256, 4) void attn_kernel(
    const _Float16* __restrict__ qh, const _Float16* __restrict__ kh,
    const _Float16* __restrict__ vt, float* __restrict__ po, float* __restrict__ pl)
{
    __shared__ __align__(16) char smem[512 * KROW + 16 * VROW];  // 12288 + 16512 = 28800
    char* sV = smem + 512 * KROW;

    const int tid = threadIdx.x;
    const int wave = __builtin_amdgcn_readfirstlane(tid >> 6);
    const int lane = tid & 63;
    const int m = lane & 31;      // key row (QK A) / V channel (PV A) / query col (C)
    const int half = lane >> 5;   // K-dim half (QK) / key quad group (PV)

    const int b = blockIdx.x;
    const int h = b & 7;
    const int qg = (b >> 3) & 15;
    const int split = b >> 7;
    const int q0 = qg * 256 + wave * 64;   // wave owns [q0, q0+64)
    const int k0 = split * KEYS_PER_SPLIT;

    const _Float16* __restrict__ qhh = qh + (size_t)h * HW * D;
    const _Float16* __restrict__ khh = kh + (size_t)h * HW * D;
    const _Float16* __restrict__ vth = vt + (size_t)h * D * HW;

    // stage K: thread t -> keys k0+t and k0+t+256, 16B data into 24B rows
    {
        const uint4 ka = *(const uint4*)(khh + (size_t)(k0 + tid) * D);
        char* da = smem + tid * KROW;
        *(uint2*)da       = make_uint2(ka.x, ka.y);
        *(uint2*)(da + 8) = make_uint2(ka.z, ka.w);
        const uint4 kb = *(const uint4*)(khh + (size_t)(k0 + 256 + tid) * D);
        char* db = smem + (256 + tid) * KROW;
        *(uint2*)db       = make_uint2(kb.x, kb.y);
        *(uint2*)(db + 8) = make_uint2(kb.z, kb.w);
    }
    // stage V: wave w -> channel rows 2w, 2w+1; lane covers 16B (8 keys) each
    {
        #pragma unroll
        for (int rr = 0; rr < 2; ++rr) {
            const int row = wave * 2 + rr;
            const uint4 vd = *(const uint4*)(vth + (size_t)row * HW + k0 + lane * 8);
            char* dst = sV + row * VROW + lane * 16;
            *(uint2*)dst       = make_uint2(vd.x, vd.y);
            *(uint2*)(dst + 8) = make_uint2(vd.z, vd.w);
        }
    }
    // ones row (channel 8) -> PV output row 8 = denominator
    *(unsigned*)(sV + 8 * VROW + tid * 4) = 0x3C003C00u;
    // rows 9-15 uninitialized: feed only unused accumulator rows

    // Q fragments (B operand): lane holds q rows q0+m / q0+32+m, dims half*4..+3
    const half4 qfA = __builtin_bit_cast(half4,
        *(const uint2*)(qhh + (size_t)(q0 + m) * D + half * 4));
    const half4 qfB = __builtin_bit_cast(half4,
        *(const uint2*)(qhh + (size_t)(q0 + 32 + m) * D + half * 4));

    __syncthreads();

    f32x16 O0 = {}, O1 = {};
    const int kBase = m * KROW + half * 8;               // into sK, +t*32*KROW
    const int vBase = (lane & 15) * VROW + half * 8;     // into sV, +t*64 + j*16

    #pragma unroll 4
    for (int t = 0; t < TILES; ++t) {
        const half4 kf = __builtin_bit_cast(half4,
            *(const uint2*)(smem + kBase + t * (32 * KROW)));
        const f32x16 zc = {};
        const f32x16 c0 = mfma32(kf, qfA, zc);   // S^T tile, q-block A
        const f32x16 c1 = mfma32(kf, qfB, zc);   // S^T tile, q-block B

        #pragma unroll
        for (int j = 0; j < 4; ++j) {
            const half4 vf = __builtin_bit_cast(half4,
                *(const uint2*)(sV + vBase + t * 64 + j * 16));
            const h2 loA = pack_h2(fast_exp2(c0[4 * j + 0]), fast_exp2(c0[4 * j + 1]));
            const h2 hiA = pack_h2(fast_exp2(c0[4 * j + 2]), fast_exp2(c0[4 * j + 3]));
            O0 = mfma32(vf, cat_h2(loA, hiA), O0);
            const h2 loB = pack_h2(fast_exp2(c1[4 * j + 0]), fast_exp2(c1[4 * j + 1]));
            const h2 hiB = pack_h2(fast_exp2(c1[4 * j + 2]), fast_exp2(c1[4 * j + 3]));
            O1 = mfma32(vf, cat_h2(loB, hiB), O1);
        }
    }

    // Epilogue: O C-layout row=(reg&3)+8*(reg>>2)+4*half, col=m.
    // half=0: regs 0-3 = channels 0-3, reg 4 = row 8 = denom; half=1: regs 0-3 = channels 4-7.
    const size_t pbase = (size_t)(split * H + h) * HW;
    *(float4*)(po + (pbase + q0 + m) * 8 + half * 4)      = make_float4(O0[0], O0[1], O0[2], O0[3]);
    *(float4*)(po + (pbase + q0 + 32 + m) * 8 + half * 4) = make_float4(O1[0], O1[1], O1[2], O1[3]);
    if (half == 0) {
        pl[pbase + q0 + m]      = O0[4];
        pl[pbase + q0 + 32 + m] = O1[4];
    }
}

// Kernel 3: 8-split combine + normalize + output projection. (unchanged)
__global__ __launch_bounds__(256) void outproj_kernel(
    const float* __restrict__ po, const float* __restrict__ pl,
    const float* __restrict__ We, const float* __restrict__ be,
    float* __restrict__ out)
{
    const int t = threadIdx.x;
    const int wave = __builtin_amdgcn_readfirstlane((int)(t >> 6));
    const int lane = t & 63;
    const int rbase = blockIdx.x * 16 + wave * 4;
    const int head = lane >> 3;
    const int d = lane & 7;

    __shared__ float sO[16][64];

    #pragma unroll
    for (int rr = 0; rr < 4; ++rr) {
        const int r = rbase + rr;
        float os = 0.f, ls = 0.f;
        #pragma unroll
        for (int s = 0; s < S; ++s) {
            os += po[((size_t)(s * H + head) * HW + r) * 8 + d];
            ls += pl[(size_t)(s * H + head) * HW + r];
        }
        sO[wave * 4 + rr][lane] = os / ls;
    }
    __syncthreads();

    const float bias = be[lane];
    float a0 = bias, a1 = bias, a2 = bias, a3 = bias;
    #pragma unroll
    for (int i4 = 0; i4 < 16; ++i4) {
        const int i = i4 * 4;
        const float4 o0 = *(const float4*)&sO[wave * 4 + 0][i];
        const float4 o1 = *(const float4*)&sO[wave * 4 + 1][i];
        const float4 o2 = *(const float4*)&sO[wave * 4 + 2][i];
        const float4 o3 = *(const float4*)&sO[wave * 4 + 3][i];
        const float w0 = We[(size_t)(i + 0) * C + lane];
        const float w1 = We[(size_t)(i + 1) * C + lane];
        const float w2 = We[(size_t)(i + 2) * C + lane];
        const float w3 = We[(size_t)(i + 3) * C + lane];
        a0 = fmaf(o0.x, w0, a0); a0 = fmaf(o0.y, w1, a0); a0 = fmaf(o0.z, w2, a0); a0 = fmaf(o0.w, w3, a0);
        a1 = fmaf(o1.x, w0, a1); a1 = fmaf(o1.y, w1, a1); a1 = fmaf(o1.z, w2, a1); a1 = fmaf(o1.w, w3, a1);
        a2 = fmaf(o2.x, w0, a2); a2 = fmaf(o2.y, w1, a2); a2 = fmaf(o2.z, w2, a2); a2 = fmaf(o2.w, w3, a2);
        a3 = fmaf(o3.x, w0, a3); a3 = fmaf(o3.y, w1, a3); a3 = fmaf(o3.z, w2, a3); a3 = fmaf(o3.w, w3, a3);
    }
    out[(size_t)(rbase + 0) * C + lane] = a0;
    out[(size_t)(rbase + 1) * C + lane] = a1;
    out[(size_t)(rbase + 2) * C + lane] = a2;
    out[(size_t)(rbase + 3) * C + lane] = a3;
}

extern "C" void kernel_launch(void* const* d_in, const int* in_sizes, int n_in,
                              void* d_out, int out_size, void* d_ws, size_t ws_size,
                              hipStream_t stream) {
    const float* x   = (const float*)d_in[0];
    const float* y   = (const float*)d_in[1];
    const float* Wq  = (const float*)d_in[2];
    const float* bq  = (const float*)d_in[3];
    const float* Wkv = (const float*)d_in[4];
    const float* bkv = (const float*)d_in[5];
    const float* We  = (const float*)d_in[6];
    const float* be  = (const float*)d_in[7];
    float* out = (float*)d_out;

    // ws layout (bytes): qh [0,512K) kh [512K,1M) vt [1M,1.5M)
    //                    po [1.5M, ~9.9M)  (S*H*HW*8 fp32)   pl [10M, ~11.1M)
    char* ws = (char*)d_ws;
    _Float16* qh = (_Float16*)(ws);
    _Float16* kh = (_Float16*)(ws + (512u << 10));
    _Float16* vt = (_Float16*)(ws + (1024u << 10));
    float*    po = (float*)   (ws + (1536u << 10));
    float*    pl = (float*)   (ws + (10240u << 10));

    hipLaunchKernelGGL(proj_kernel, dim3(HW / 4), dim3(192), 0, stream,
                       x, y, Wq, bq, Wkv, bkv, qh, kh, vt);
    hipLaunchKernelGGL(attn_kernel, dim3(H * (HW / 256) * S), dim3(256), 0, stream,
                       qh, kh, vt, po, pl);
    hipLaunchKernelGGL(outproj_kernel, dim3(HW / 16), dim3(256), 0, stream,
                       po, pl, We, be, out);
}